// Round 12
// baseline (218.717 us; speedup 1.0000x reference)
//
#include <hip/hip_runtime.h>
#include <hip/hip_bf16.h>
#include <cstdint>

typedef __attribute__((ext_vector_type(8))) short bf16x8;
typedef __attribute__((ext_vector_type(4))) float f32x4;
typedef __attribute__((ext_vector_type(16))) float f32x16;
typedef __attribute__((ext_vector_type(4), aligned(4))) float f32x4u;  // 4B-aligned vec load
typedef __attribute__((ext_vector_type(4))) int i32x4;

constexpr int Tt = 12, Nn = 325, DKk = 32;
constexpr int NSLICE = 1536;              // B*H*T
constexpr int SLICE  = Nn * DKk;          // 10400
constexpr int BIASE  = Nn * Nn;           // 105625
constexpr int KSTR = 40;                  // K LDS row stride (shorts): 80B rows, 16B-aligned
constexpr int VSTR = 360;                 // V^T LDS row stride (shorts); cols 325..359 zeroed

__device__ __forceinline__ unsigned short f2bf(float f) {
  union { float f; uint32_t u; } v; v.f = f;
  uint32_t u = v.u;
  uint32_t r = u + 0x7FFFu + ((u >> 16) & 1u);   // RNE
  return (unsigned short)(r >> 16);
}
__device__ __forceinline__ uint32_t pack2(float a, float b) {
  return (uint32_t)f2bf(a) | ((uint32_t)f2bf(b) << 16);
}

__global__ __launch_bounds__(256, 3)
void attn_kernel(const float* __restrict__ Q, const float* __restrict__ K,
                 const float* __restrict__ V, const float* __restrict__ Bias,
                 float* __restrict__ Out)
{
  __shared__ short lds_k[325 * KSTR];        // 26.0 KB
  __shared__ short lds_vt[32 * VSTR];        // 23.0 KB
  // 49.0 KB total -> 3 blocks/CU. In-register softmax; crossbar via shfl_xor(32)
  // (validated primitives only this round: bisecting the 32x32 layout).

  // XCD-grouped remap: 12 t-slices of one (b,h) on one XCD -> bias L2-resident
  const int bid = blockIdx.x;
  const int x = bid & 7, u = bid >> 3;
  const int s = (((u / Tt) << 3) + x) * Tt + (u % Tt);

  const int bh = s / Tt;
  const size_t base  = (size_t)s * SLICE;
  const size_t bbase = (size_t)bh * BIASE;
  const int tid = threadIdx.x;

  // ---- stage K as bf16 ----
  for (int i = tid; i < SLICE / 2; i += 256) {
    const int e0 = i << 1;
    const int row = e0 >> 5, col = e0 & 31;
    const float2 f = *(const float2*)(K + base + e0);
    *(uint32_t*)&lds_k[row * KSTR + col] = pack2(f.x, f.y);
  }
  // ---- stage V^T as bf16 (col 325 zeroed here via the j0+1 guard) ----
  for (int i = tid; i < 32 * 163; i += 256) {
    const int d = i & 31, jp = i >> 5;
    const int j0 = jp << 1;
    const float a  = V[base + (size_t)j0 * DKk + d];
    const float b2 = (j0 + 1 < Nn) ? V[base + (size_t)(j0 + 1) * DKk + d] : 0.f;
    *(uint32_t*)&lds_vt[d * VSTR + j0] = pack2(a, b2);
  }
  // ---- zero V^T pad cols 326..359 (kb=10 reads reach col 351) ----
  for (int i = tid; i < 32 * 34; i += 256) {
    const int d = i / 34, c = 326 + (i - d * 34);
    lds_vt[d * VSTR + c] = 0;
  }
  __syncthreads();

  const int wave = tid >> 6, lane = tid & 63;
  const int l31 = lane & 31;                 // q-column / d-row within tile
  const int h   = lane >> 5;                 // half selector
  const int h8  = h << 3, h4 = h << 2;
  const float scale = 0.17677669529663687f;  // 1/sqrt(32), folded into Q
  const float* __restrict__ bb = Bias + bbase;

  auto process = [&](const int qt0, const int qt1, const bool two) {
    const int qtn = two ? 2 : 1;
    int qb[2]   = { qt0 << 5, qt1 << 5 };
    int qoff[2];                              // clamped bias/Q row offset
    bf16x8 bq1[2], bq2[2];                    // Q B-frags (dims 0..15 / 16..31)
    #pragma unroll
    for (int t = 0; t < 2; ++t) {
      if (t >= qtn) break;
      int q = qb[t] + l31; q = q < Nn ? q : (Nn - 1);
      qoff[t] = q * Nn;
      const float* p = Q + base + (size_t)q * DKk;
      const float4 a0 = *(const float4*)(p + h8);
      const float4 a1 = *(const float4*)(p + h8 + 4);
      const float4 a2 = *(const float4*)(p + 16 + h8);
      const float4 a3 = *(const float4*)(p + 16 + h8 + 4);
      bq1[t][0]=(short)f2bf(a0.x*scale); bq1[t][1]=(short)f2bf(a0.y*scale);
      bq1[t][2]=(short)f2bf(a0.z*scale); bq1[t][3]=(short)f2bf(a0.w*scale);
      bq1[t][4]=(short)f2bf(a1.x*scale); bq1[t][5]=(short)f2bf(a1.y*scale);
      bq1[t][6]=(short)f2bf(a1.z*scale); bq1[t][7]=(short)f2bf(a1.w*scale);
      bq2[t][0]=(short)f2bf(a2.x*scale); bq2[t][1]=(short)f2bf(a2.y*scale);
      bq2[t][2]=(short)f2bf(a2.z*scale); bq2[t][3]=(short)f2bf(a2.w*scale);
      bq2[t][4]=(short)f2bf(a3.x*scale); bq2[t][5]=(short)f2bf(a3.y*scale);
      bq2[t][6]=(short)f2bf(a3.z*scale); bq2[t][7]=(short)f2bf(a3.w*scale);
    }

    f32x16 acc[2];
    float rsl[2] = { 0.f, 0.f };
    #pragma unroll
    for (int t = 0; t < 2; ++t) {
      #pragma unroll
      for (int r = 0; r < 16; ++r) acc[t][r] = 0.f;
    }

    #pragma unroll
    for (int kb = 0; kb < 11; ++kb) {
      const int j0 = kb << 5;
      // K A-frags (row=key=j0+l31, k=8h+e; dim halves 0..15 / 16..31)
      int krow = j0 + l31;
      if (kb == 10) krow = krow < Nn ? krow : (Nn - 1);
      const bf16x8 bk1 = *(const bf16x8*)&lds_k[krow * KSTR + h8];
      const bf16x8 bk2 = *(const bf16x8*)&lds_k[krow * KSTR + 16 + h8];
      // V^T A-frags (row=d=l31, k=8h+e -> key j0+8h+e / j0+16+8h+e)
      const bf16x8 bv1 = *(const bf16x8*)&lds_vt[l31 * VSTR + j0 + h8];
      const bf16x8 bv2 = *(const bf16x8*)&lds_vt[l31 * VSTR + j0 + 16 + h8];

      #pragma unroll
      for (int t = 0; t < 2; ++t) {
        if (t >= qtn) break;
        // S^T tile: col q=l31, row key=j0+crow(r,h), crow=(r&3)+8(r>>2)+4h
        f32x16 st = __builtin_amdgcn_mfma_f32_32x32x16_bf16(bk1, bq1[t], (f32x16)(0.f), 0, 0, 0);
        st = __builtin_amdgcn_mfma_f32_32x32x16_bf16(bk2, bq2[t], st, 0, 0, 0);

        float p[16];
        if (kb < 10) {
          // bias: 4x contiguous float4 (row q, keys j0+8g+4h+0..3)
          f32x4u bg[4];
          #pragma unroll
          for (int g = 0; g < 4; ++g)
            bg[g] = *(const f32x4u*)&bb[qoff[t] + j0 + (g << 3) + h4];
          #pragma unroll
          for (int r = 0; r < 16; ++r) {
            p[r] = __expf(st[r] + bg[r >> 2][r & 3]);
            rsl[t] += p[r];
          }
        } else {
          // tail: keys 320+crow; scalar clamped bias, mask pad keys -> p=0
          #pragma unroll
          for (int r = 0; r < 16; ++r) {
            const int key = 320 + (r & 3) + ((r >> 2) << 3) + h4;
            const int keyc = key < Nn ? key : (Nn - 1);
            float xv = st[r] + bb[qoff[t] + keyc];
            xv = key < Nn ? xv : -1e30f;
            p[r] = __expf(xv);
            rsl[t] += p[r];
          }
        }

        // pack consecutive-key pairs (validated pack2), then cross-half exchange
        // via UNCONDITIONAL full-wave shfl_xor(32); divergent select only after,
        // on defined values (round-9-validated pattern).
        int pk[8], xk[8];
        #pragma unroll
        for (int g = 0; g < 8; ++g) pk[g] = (int)pack2(p[2 * g], p[2 * g + 1]);
        #pragma unroll
        for (int g = 0; g < 8; ++g) xk[g] = __shfl_xor(pk[g], 32, 64);
        // h=0 holds keys {0-3,8-11,16-19,24-27}; partner holds the rest.
        union { i32x4 i; bf16x8 hh; } pa1, pa2;
        pa1.i[0] = h ? xk[2] : pk[0];   // frag1 -> keys j0+(8h..8h+7)
        pa1.i[1] = h ? xk[3] : pk[1];
        pa1.i[2] = h ? pk[2] : xk[0];
        pa1.i[3] = h ? pk[3] : xk[1];
        pa2.i[0] = h ? xk[6] : pk[4];   // frag2 -> keys j0+16+(8h..8h+7)
        pa2.i[1] = h ? xk[7] : pk[5];
        pa2.i[2] = h ? pk[6] : xk[4];
        pa2.i[3] = h ? pk[7] : xk[5];

        // O^T accumulate: A=V^T frag (row=d), B=P^T (col=q)
        acc[t] = __builtin_amdgcn_mfma_f32_32x32x16_bf16(bv1, pa1.hh, acc[t], 0, 0, 0);
        acc[t] = __builtin_amdgcn_mfma_f32_32x32x16_bf16(bv2, pa2.hh, acc[t], 0, 0, 0);
      }
    }

    // epilogue: denom (q lives in lanes l, l^32), normalize, store O^T
    #pragma unroll
    for (int t = 0; t < 2; ++t) {
      if (t >= qtn) break;
      const float denom = rsl[t] + __shfl_xor(rsl[t], 32, 64);
      const float inv = 1.f / denom;
      const int q = qb[t] + l31;
      if (q < Nn) {
        float* op = Out + base + (size_t)q * DKk;
        #pragma unroll
        for (int g = 0; g < 4; ++g) {
          // C/D rows d = 8g + 4h + {0..3} (regs 4g..4g+3)
          float4 o;
          o.x = acc[t][4 * g + 0] * inv;
          o.y = acc[t][4 * g + 1] * inv;
          o.z = acc[t][4 * g + 2] * inv;
          o.w = acc[t][4 * g + 3] * inv;
          *(float4*)(op + (g << 3) + h4) = o;
        }
      }
    }
  };

  // Coverage: 11 q-tiles of 32 rows. Call 1: pairs (w, w+4) -> tiles 0..7.
  // Call 2: waves 0..2 single tiles 8..10 (wave 3 idle). Each tile exactly once.
  process(wave, wave + 4, true);
  if (wave < 3) process(wave + 8, wave + 8, false);
}

extern "C" void kernel_launch(void* const* d_in, const int* in_sizes, int n_in,
                              void* d_out, int out_size, void* d_ws, size_t ws_size,
                              hipStream_t stream) {
  const float* Q    = (const float*)d_in[0];
  const float* K    = (const float*)d_in[1];
  const float* V    = (const float*)d_in[2];
  const float* Bias = (const float*)d_in[3];
  float* Out = (float*)d_out;
  attn_kernel<<<dim3(NSLICE), dim3(256), 0, stream>>>(Q, K, V, Bias, Out);
}